// Round 2
// baseline (1541.005 us; speedup 1.0000x reference)
//
#include <hip/hip_runtime.h>
#include <hip/hip_bf16.h>

using bf16 = __hip_bfloat16;

constexpr int B  = 8;
constexpr int N0 = 8192;
constexpr int NS = 2048;
constexpr int CP = 512;
constexpr int CS = 256;
constexpr int C1 = 256;
constexpr int C2 = 256;
constexpr int K1 = CP + CS;          // 768
constexpr int COLS = B * N0;         // 65536
constexpr float BN_EPS = 1e-3f;
constexpr float SLOPE  = 0.01f;

__device__ __forceinline__ float b2f(bf16 v) { return __bfloat162float(v); }

struct alignas(8) bf16x4 { bf16 h[4]; };

__device__ __forceinline__ void fma4(float4& c, float a, const float4& b) {
  c.x += a * b.x; c.y += a * b.y; c.z += a * b.z; c.w += a * b.w;
}

// ---------------- prep: transpose weights to [K][M], zero stats ----------------
__global__ __launch_bounds__(256) void prep_kernel(
    const float* __restrict__ W1, const float* __restrict__ W2,
    float* __restrict__ W1t, float* __restrict__ W2t, float* __restrict__ stats)
{
  int id = blockIdx.x * 256 + threadIdx.x;
  if (id < 1024) stats[id] = 0.0f;
  if (id < K1 * C1) { int o = id % C1, k = id / C1; W1t[id] = W1[o * K1 + k]; }
  if (id < C1 * C2) { int o = id % C2, k = id / C2; W2t[id] = W2[o * C1 + k]; }
}

// ---------------- 3-NN: indices + inverse-distance weights ----------------
__global__ __launch_bounds__(256) void knn_kernel(
    const float* __restrict__ xyz, const float* __restrict__ xyz_prev,
    float* __restrict__ wq, int* __restrict__ iq)
{
#pragma clang fp contract(off)
  __shared__ float sx[NS], sy[NS], sz[NS], sq[NS];
  const int b = blockIdx.y;
  const float* xp = xyz_prev + (size_t)b * 3 * NS;
  for (int j = threadIdx.x; j < NS; j += 256) {
    float x = xp[j], y = xp[NS + j], z = xp[2 * NS + j];
    sx[j] = x; sy[j] = y; sz[j] = z;
    sq[j] = (x * x + y * y) + z * z;             // numpy association
  }
  __syncthreads();
  const int n = blockIdx.x * 256 + threadIdx.x;
  const float* xq = xyz + (size_t)b * 3 * N0;
  float qx = xq[n], qy = xq[N0 + n], qz = xq[2 * N0 + n];
  float qq = (qx * qx + qy * qy) + qz * qz;

  float d0 = 1e30f, d1 = 1e30f, d2 = 1e30f;
  int   i0 = 0, i1 = 0, i2 = 0;
  for (int j = 0; j < NS; ++j) {
    float dot = (qx * sx[j] + qy * sy[j]) + qz * sz[j];
    float d = (qq + sq[j]) - 2.0f * dot;         // numpy association
    if (d < d0)      { d2 = d1; i2 = i1; d1 = d0; i1 = i0; d0 = d; i0 = j; }
    else if (d < d1) { d2 = d1; i2 = i1; d1 = d;  i1 = j; }
    else if (d < d2) { d2 = d;  i2 = j; }
  }
  d0 = fmaxf(d0, 1e-10f); d1 = fmaxf(d1, 1e-10f); d2 = fmaxf(d2, 1e-10f);
  float v0 = 1.0f / (d0 + 1e-8f), v1 = 1.0f / (d1 + 1e-8f), v2 = 1.0f / (d2 + 1e-8f);
  float s = (v0 + v1) + v2;
  const int gi = (b * N0 + n) * 3;
  wq[gi + 0] = v0 / s; wq[gi + 1] = v1 / s; wq[gi + 2] = v2 / s;
  iq[gi + 0] = i0;     iq[gi + 1] = i1;     iq[gi + 2] = i2;
}

// ---------------- GEMM1: Y1 = W1 * [interp(feat_prev); skip], + BN1 stats ----------------
__global__ __launch_bounds__(256) void gemm1_kernel(
    const float* __restrict__ W1t, const float* __restrict__ feat_prev,
    const float* __restrict__ skip, const int* __restrict__ iq,
    const float* __restrict__ wq, bf16* __restrict__ Y1, float* __restrict__ stats)
{
  __shared__ float Ws[16][256];
  __shared__ float Xs[16][64];
  __shared__ int   ci[192];
  __shared__ float cw[192];

  const int tid = threadIdx.x;
  const int b   = blockIdx.y;
  const int n0  = blockIdx.x * 64;

  if (tid < 192) {
    int q = (b * N0 + n0) * 3 + tid;
    ci[tid] = iq[q];
    cw[tid] = wq[q];
  }

  float4 acc[16];
#pragma unroll
  for (int i = 0; i < 16; ++i) acc[i] = make_float4(0.f, 0.f, 0.f, 0.f);

  const int rb = (tid >> 4) << 4;   // 16 rows per thread
  const int cb = (tid & 15) << 2;   // 4 cols per thread

  for (int kt = 0; kt < K1 / 16; ++kt) {
    __syncthreads();
    // stage W tile: 16 x 256 fp32
#pragma unroll
    for (int i = 0; i < 4; ++i) {
      int q4 = tid + 256 * i;
      int kk = q4 >> 6, m4 = q4 & 63;
      reinterpret_cast<float4*>(&Ws[kk][0])[m4] =
          reinterpret_cast<const float4*>(W1t + (size_t)(kt * 16 + kk) * 256)[m4];
    }
    // stage X tile: 16 x 64 (interp gather or skip)
#pragma unroll
    for (int i = 0; i < 4; ++i) {
      int p = tid + 256 * i;
      int kk = p >> 6, col = p & 63;
      int c = kt * 16 + kk;
      float v;
      if (c < CP) {
        const float* fp = feat_prev + (size_t)(b * CP + c) * NS;
        v = cw[col * 3 + 0] * fp[ci[col * 3 + 0]]
          + cw[col * 3 + 1] * fp[ci[col * 3 + 1]]
          + cw[col * 3 + 2] * fp[ci[col * 3 + 2]];
      } else {
        v = skip[(size_t)(b * CS + (c - CP)) * N0 + n0 + col];
      }
      Xs[kk][col] = v;
    }
    __syncthreads();
#pragma unroll
    for (int kk = 0; kk < 16; ++kk) {
      float4 bx = *reinterpret_cast<const float4*>(&Xs[kk][cb]);
#pragma unroll
      for (int i4 = 0; i4 < 4; ++i4) {
        float4 a = *reinterpret_cast<const float4*>(&Ws[kk][rb + i4 * 4]);
        fma4(acc[i4 * 4 + 0], a.x, bx);
        fma4(acc[i4 * 4 + 1], a.y, bx);
        fma4(acc[i4 * 4 + 2], a.z, bx);
        fma4(acc[i4 * 4 + 3], a.w, bx);
      }
    }
  }

  const int gcol = b * N0 + n0 + cb;
#pragma unroll
  for (int i = 0; i < 16; ++i) {
    int r = rb + i;
    float4 v = acc[i];
    bf16x4 o;
    o.h[0] = __float2bfloat16(v.x); o.h[1] = __float2bfloat16(v.y);
    o.h[2] = __float2bfloat16(v.z); o.h[3] = __float2bfloat16(v.w);
    *reinterpret_cast<bf16x4*>(Y1 + (size_t)r * COLS + gcol) = o;

    float ps  = (v.x + v.y) + (v.z + v.w);
    float pss = (v.x * v.x + v.y * v.y) + (v.z * v.z + v.w * v.w);
#pragma unroll
    for (int m = 1; m < 16; m <<= 1) { ps += __shfl_xor(ps, m); pss += __shfl_xor(pss, m); }
    if ((tid & 15) == 0) {
      atomicAdd(&stats[r], ps);
      atomicAdd(&stats[C1 + r], pss);
    }
  }
}

// ---------------- affine: fold BN stats + gamma/beta into scale/shift ----------------
__global__ __launch_bounds__(256) void affine_kernel(
    const float* __restrict__ s, const float* __restrict__ g,
    const float* __restrict__ bb, float* __restrict__ a)
{
  int c = threadIdx.x;
  float inv = 1.0f / (float)COLS;
  float mean = s[c] * inv;
  float var  = s[C1 + c] * inv - mean * mean;
  float sc   = g[c] / sqrtf(var + BN_EPS);
  a[c]      = sc;
  a[C1 + c] = bb[c] - mean * sc;
}

// ---------------- GEMM2: Y2raw = W2 * lrelu(bn1(Y1)), + BN2 stats ----------------
__global__ __launch_bounds__(256) void gemm2_kernel(
    const float* __restrict__ W2t, const bf16* __restrict__ Y1,
    const float* __restrict__ aff, float* __restrict__ out_nf, float* __restrict__ stats2)
{
  __shared__ float Ws[16][256];
  __shared__ float Xs[16][64];

  const int tid = threadIdx.x;
  const int b   = blockIdx.y;
  const int n0  = blockIdx.x * 64;

  float4 acc[16];
#pragma unroll
  for (int i = 0; i < 16; ++i) acc[i] = make_float4(0.f, 0.f, 0.f, 0.f);

  const int rb = (tid >> 4) << 4;
  const int cb = (tid & 15) << 2;

  for (int kt = 0; kt < C1 / 16; ++kt) {
    __syncthreads();
#pragma unroll
    for (int i = 0; i < 4; ++i) {
      int q4 = tid + 256 * i;
      int kk = q4 >> 6, m4 = q4 & 63;
      reinterpret_cast<float4*>(&Ws[kk][0])[m4] =
          reinterpret_cast<const float4*>(W2t + (size_t)(kt * 16 + kk) * 256)[m4];
    }
#pragma unroll
    for (int i = 0; i < 4; ++i) {
      int p = tid + 256 * i;
      int kk = p >> 6, col = p & 63;
      int c = kt * 16 + kk;
      float v = b2f(Y1[(size_t)c * COLS + b * N0 + n0 + col]);
      v = v * aff[c] + aff[C1 + c];
      v = (v >= 0.f) ? v : SLOPE * v;
      Xs[kk][col] = v;
    }
    __syncthreads();
#pragma unroll
    for (int kk = 0; kk < 16; ++kk) {
      float4 bx = *reinterpret_cast<const float4*>(&Xs[kk][cb]);
#pragma unroll
      for (int i4 = 0; i4 < 4; ++i4) {
        float4 a = *reinterpret_cast<const float4*>(&Ws[kk][rb + i4 * 4]);
        fma4(acc[i4 * 4 + 0], a.x, bx);
        fma4(acc[i4 * 4 + 1], a.y, bx);
        fma4(acc[i4 * 4 + 2], a.z, bx);
        fma4(acc[i4 * 4 + 3], a.w, bx);
      }
    }
  }

  const int ncol = n0 + cb;
#pragma unroll
  for (int i = 0; i < 16; ++i) {
    int r = rb + i;
    float4 v = acc[i];
    *reinterpret_cast<float4*>(out_nf + (size_t)(b * C2 + r) * N0 + ncol) = v;

    float ps  = (v.x + v.y) + (v.z + v.w);
    float pss = (v.x * v.x + v.y * v.y) + (v.z * v.z + v.w * v.w);
#pragma unroll
    for (int m = 1; m < 16; m <<= 1) { ps += __shfl_xor(ps, m); pss += __shfl_xor(pss, m); }
    if ((tid & 15) == 0) {
      atomicAdd(&stats2[r], ps);
      atomicAdd(&stats2[C2 + r], pss);
    }
  }
}

// ---------------- finalize: in-place BN2 + LeakyReLU on out_nf (fp32) ----------------
__global__ __launch_bounds__(256) void finalize_kernel(float* __restrict__ nf,
                                                       const float* __restrict__ aff)
{
  int id4 = blockIdx.x * 256 + threadIdx.x;      // float4-granule index
  int e = id4 * 4;
  int c = (e % (C2 * N0)) / N0;
  float sc = aff[c], sh = aff[C1 + c];
  float4 v = reinterpret_cast<float4*>(nf)[id4];
  v.x = v.x * sc + sh; v.x = (v.x >= 0.f) ? v.x : SLOPE * v.x;
  v.y = v.y * sc + sh; v.y = (v.y >= 0.f) ? v.y : SLOPE * v.y;
  v.z = v.z * sc + sh; v.z = (v.z >= 0.f) ? v.z : SLOPE * v.z;
  v.w = v.w * sc + sh; v.w = (v.w >= 0.f) ? v.w : SLOPE * v.w;
  reinterpret_cast<float4*>(nf)[id4] = v;
}

// ---------------- copy xyz passthrough (fp32) ----------------
__global__ __launch_bounds__(256) void copy_xyz_kernel(const float* __restrict__ xyz,
                                                       float* __restrict__ out)
{
  int id = blockIdx.x * 256 + threadIdx.x;       // float4 granules, 12288 total
  reinterpret_cast<float4*>(out)[id] = reinterpret_cast<const float4*>(xyz)[id];
}

extern "C" void kernel_launch(void* const* d_in, const int* in_sizes, int n_in,
                              void* d_out, int out_size, void* d_ws, size_t ws_size,
                              hipStream_t stream)
{
  const float* xyz       = (const float*)d_in[0];
  const float* skip      = (const float*)d_in[1];
  const float* xyz_prev  = (const float*)d_in[2];
  const float* feat_prev = (const float*)d_in[3];
  const float* W1        = (const float*)d_in[4];
  const float* g1        = (const float*)d_in[5];
  const float* b1        = (const float*)d_in[6];
  const float* W2        = (const float*)d_in[7];
  const float* g2        = (const float*)d_in[8];
  const float* b2        = (const float*)d_in[9];

  float* out    = (float*)d_out;
  float* out_nf = out + (size_t)B * 3 * N0;      // [B][C2][N0] fp32

  char* ws = (char*)d_ws;
  float* wq    = (float*)(ws + 0);               // 196608 f  (786432 B)
  int*   iq    = (int*)  (ws + 786432);          // 196608 i  (786432 B)
  float* W1t   = (float*)(ws + 1572864);         // 768*256 f (786432 B)
  float* W2t   = (float*)(ws + 2359296);         // 256*256 f (262144 B)
  float* stats = (float*)(ws + 2621440);         // 1024 f    (4096 B)
  float* aff   = (float*)(ws + 2625536);         // 1024 f    (4096 B)
  bf16*  Y1    = (bf16*) (ws + 2629632);         // 256*65536 bf16 (33554432 B)
  // total: 36,184,064 B

  prep_kernel<<<768, 256, 0, stream>>>(W1, W2, W1t, W2t, stats);
  knn_kernel<<<dim3(N0 / 256, B), 256, 0, stream>>>(xyz, xyz_prev, wq, iq);
  gemm1_kernel<<<dim3(N0 / 64, B), 256, 0, stream>>>(W1t, feat_prev, skip, iq, wq, Y1, stats);
  affine_kernel<<<1, 256, 0, stream>>>(stats, g1, b1, aff);
  gemm2_kernel<<<dim3(N0 / 64, B), 256, 0, stream>>>(W2t, Y1, aff, out_nf, stats + 512);
  affine_kernel<<<1, 256, 0, stream>>>(stats + 512, g2, b2, aff + 512);
  finalize_kernel<<<(C2 * N0 * B) / (4 * 256), 256, 0, stream>>>(out_nf, aff + 512);
  copy_xyz_kernel<<<(B * 3 * N0) / (4 * 256), 256, 0, stream>>>(xyz, out);
}

// Round 3
// 985.362 us; speedup vs baseline: 1.5639x; 1.5639x over previous
//
#include <hip/hip_runtime.h>
#include <hip/hip_bf16.h>

using bf16 = __hip_bfloat16;

constexpr int B  = 8;
constexpr int N0 = 8192;
constexpr int NS = 2048;
constexpr int CP = 512;
constexpr int CS = 256;
constexpr int C1 = 256;
constexpr int C2 = 256;
constexpr int K1 = CP + CS;          // 768
constexpr int COLS = B * N0;         // 65536
constexpr float BN_EPS = 1e-3f;
constexpr float SLOPE  = 0.01f;

typedef short  short8 __attribute__((ext_vector_type(8)));
typedef float  f32x4  __attribute__((ext_vector_type(4)));

// manual RNE fp32->bf16 (no NaNs in this workload) and back
__device__ __forceinline__ unsigned short f2bu(float f) {
  unsigned int u = __float_as_uint(f);
  return (unsigned short)((u + 0x7fffu + ((u >> 16) & 1u)) >> 16);
}
__device__ __forceinline__ float bu2f(unsigned short v) {
  return __uint_as_float((unsigned int)v << 16);
}

// ---------------- prep: fp32 weights -> bf16 (row-major [M][K]), zero stats ----------------
__global__ __launch_bounds__(256) void prep_kernel(
    const float* __restrict__ W1, const float* __restrict__ W2,
    unsigned short* __restrict__ W1b, unsigned short* __restrict__ W2b,
    float* __restrict__ stats)
{
  int id = blockIdx.x * 256 + threadIdx.x;
  if (id < 1024) stats[id] = 0.0f;
  if (id < C1 * K1) W1b[id] = f2bu(W1[id]);
  if (id < C2 * C1) W2b[id] = f2bu(W2[id]);
}

// ---------------- 3-NN: indices + inverse-distance weights ----------------
__global__ __launch_bounds__(256) void knn_kernel(
    const float* __restrict__ xyz, const float* __restrict__ xyz_prev,
    float* __restrict__ wq, int* __restrict__ iq)
{
#pragma clang fp contract(off)
  __shared__ float4 sp[NS];                       // x,y,z,|p|^2  (32 KB)
  const int b = blockIdx.y;
  const float* xp = xyz_prev + (size_t)b * 3 * NS;
  for (int j = threadIdx.x; j < NS; j += 256) {
    float x = xp[j], y = xp[NS + j], z = xp[2 * NS + j];
    sp[j] = make_float4(x, y, z, (x * x + y * y) + z * z);   // numpy association
  }
  __syncthreads();
  const int n = blockIdx.x * 256 + threadIdx.x;
  const float* xq = xyz + (size_t)b * 3 * N0;
  float qx = xq[n], qy = xq[N0 + n], qz = xq[2 * N0 + n];
  float qq = (qx * qx + qy * qy) + qz * qz;

  float d0 = 1e30f, d1 = 1e30f, d2 = 1e30f;
  int   i0 = 0, i1 = 0, i2 = 0;
  for (int j = 0; j < NS; ++j) {
    float4 p = sp[j];
    float dot = (qx * p.x + qy * p.y) + qz * p.z;
    float d = (qq + p.w) - 2.0f * dot;            // numpy association
    if (d < d0)      { d2 = d1; i2 = i1; d1 = d0; i1 = i0; d0 = d; i0 = j; }
    else if (d < d1) { d2 = d1; i2 = i1; d1 = d;  i1 = j; }
    else if (d < d2) { d2 = d;  i2 = j; }
  }
  d0 = fmaxf(d0, 1e-10f); d1 = fmaxf(d1, 1e-10f); d2 = fmaxf(d2, 1e-10f);
  float v0 = 1.0f / (d0 + 1e-8f), v1 = 1.0f / (d1 + 1e-8f), v2 = 1.0f / (d2 + 1e-8f);
  float s = (v0 + v1) + v2;
  const int gi = (b * N0 + n) * 3;
  wq[gi + 0] = v0 / s; wq[gi + 1] = v1 / s; wq[gi + 2] = v2 / s;
  iq[gi + 0] = i0;     iq[gi + 1] = i1;     iq[gi + 2] = i2;
}

// =======================================================================
// MFMA GEMM1: Y1t[n][c1] = (W1 * [interp(feat_prev); skip])^T  + BN1 stats
// grid (512, 2): x -> (b = x>>6, nbase = (x&63)*128), y -> bm (M-half)
// =======================================================================
__global__ __launch_bounds__(256) void gemm1_kernel(
    const unsigned short* __restrict__ W1b, const float* __restrict__ feat_prev,
    const float* __restrict__ skip, const int* __restrict__ iq,
    const float* __restrict__ wq, unsigned short* __restrict__ Y1t,
    float* __restrict__ stats)
{
  __shared__ unsigned short As[128][72];   // [m][k], +8 pad -> 2-way bank alias (free)
  __shared__ unsigned short Bs[128][72];   // [n][k]

  const int tid   = threadIdx.x;
  const int b     = blockIdx.x >> 6;
  const int nbase = (blockIdx.x & 63) * 128;
  const int bm    = blockIdx.y;

  // per-thread B-staging column: fixed across K-loop -> preload idx/weights
  const int sn = tid & 127;
  const int kh = tid >> 7;                 // 0/1: which 32-wide k-half this thread stages
  const int gcol_s = b * N0 + nbase + sn;
  const int gq = gcol_s * 3;
  const int i0 = iq[gq], i1 = iq[gq + 1], i2 = iq[gq + 2];
  const float w0 = wq[gq], w1 = wq[gq + 1], w2 = wq[gq + 2];
  const float* fpb = feat_prev + (size_t)b * CP * NS;

  const int wv = tid >> 6, lane = tid & 63;
  const int wm = (wv & 1) * 64, wn = (wv >> 1) * 64;
  const int qm = lane & 15, quad = lane >> 4;

  f32x4 acc[4][4];
#pragma unroll
  for (int i = 0; i < 4; ++i)
#pragma unroll
    for (int j = 0; j < 4; ++j) acc[i][j] = (f32x4){0.f, 0.f, 0.f, 0.f};

  for (int kt = 0; kt < K1 / 64; ++kt) {
    __syncthreads();
    // ---- stage A: W1b rows [bm*128 .. +128), k [kt*64 .. +64) ----
#pragma unroll
    for (int i = 0; i < 4; ++i) {
      int id = tid + 256 * i;              // 1024 16B-chunks
      int r = id >> 3, ck = id & 7;
      *reinterpret_cast<short8*>(&As[r][ck * 8]) =
          *reinterpret_cast<const short8*>(W1b + (size_t)(bm * 128 + r) * K1 + kt * 64 + ck * 8);
    }
    // ---- stage B: X tile [128 n][64 k]; interp (c<512) or skip ----
    const int cbase = kt * 64 + kh * 32;
    if (cbase < CP) {
#pragma unroll
      for (int g = 0; g < 4; ++g) {
        alignas(16) unsigned short tmp[8];
#pragma unroll
        for (int j = 0; j < 8; ++j) {
          const float* fp = fpb + (size_t)(cbase + g * 8 + j) * NS;
          tmp[j] = f2bu(w0 * fp[i0] + w1 * fp[i1] + w2 * fp[i2]);
        }
        *reinterpret_cast<short8*>(&Bs[sn][kh * 32 + g * 8]) =
            *reinterpret_cast<const short8*>(tmp);
      }
    } else {
#pragma unroll
      for (int g = 0; g < 4; ++g) {
        alignas(16) unsigned short tmp[8];
#pragma unroll
        for (int j = 0; j < 8; ++j) {
          int cs = cbase - CP + g * 8 + j;
          tmp[j] = f2bu(skip[((size_t)b * CS + cs) * N0 + nbase + sn]);
        }
        *reinterpret_cast<short8*>(&Bs[sn][kh * 32 + g * 8]) =
            *reinterpret_cast<const short8*>(tmp);
      }
    }
    __syncthreads();
    // ---- MFMA: 2 k32 halves x 4x4 fragments ----
#pragma unroll
    for (int h = 0; h < 2; ++h) {
      short8 af[4], bf[4];
#pragma unroll
      for (int i = 0; i < 4; ++i)
        af[i] = *reinterpret_cast<const short8*>(&As[wm + i * 16 + qm][h * 32 + quad * 8]);
#pragma unroll
      for (int j = 0; j < 4; ++j)
        bf[j] = *reinterpret_cast<const short8*>(&Bs[wn + j * 16 + qm][h * 32 + quad * 8]);
#pragma unroll
      for (int i = 0; i < 4; ++i)
#pragma unroll
        for (int j = 0; j < 4; ++j)
          acc[i][j] = __builtin_amdgcn_mfma_f32_16x16x32_bf16(af[i], bf[j], acc[i][j], 0, 0, 0);
    }
  }

  // ---- epilogue: store Y1t[n][c] bf16 (8B per fragment) + BN1 stats ----
#pragma unroll
  for (int i = 0; i < 4; ++i) {
    const int mb = bm * 128 + wm + i * 16 + quad * 4;
    float s[4] = {0.f, 0.f, 0.f, 0.f}, s2[4] = {0.f, 0.f, 0.f, 0.f};
#pragma unroll
    for (int j = 0; j < 4; ++j) {
      const int gc = b * N0 + nbase + wn + j * 16 + qm;
      ushort4 o;
      o.x = f2bu(acc[i][j][0]); o.y = f2bu(acc[i][j][1]);
      o.z = f2bu(acc[i][j][2]); o.w = f2bu(acc[i][j][3]);
      *reinterpret_cast<ushort4*>(Y1t + (size_t)gc * C1 + mb) = o;
#pragma unroll
      for (int r = 0; r < 4; ++r) {
        float v = acc[i][j][r];
        s[r] += v; s2[r] += v * v;
      }
    }
#pragma unroll
    for (int m = 1; m < 16; m <<= 1) {
#pragma unroll
      for (int r = 0; r < 4; ++r) { s[r] += __shfl_xor(s[r], m); s2[r] += __shfl_xor(s2[r], m); }
    }
    if (qm == 0) {
#pragma unroll
      for (int r = 0; r < 4; ++r) {
        atomicAdd(&stats[mb + r], s[r]);
        atomicAdd(&stats[C1 + mb + r], s2[r]);
      }
    }
  }
}

// ---------------- affine: fold BN stats + gamma/beta into scale/shift ----------------
__global__ __launch_bounds__(256) void affine_kernel(
    const float* __restrict__ s, const float* __restrict__ g,
    const float* __restrict__ bb, float* __restrict__ a)
{
  int c = threadIdx.x;
  float inv = 1.0f / (float)COLS;
  float mean = s[c] * inv;
  float var  = s[C1 + c] * inv - mean * mean;
  float sc   = g[c] / sqrtf(var + BN_EPS);
  a[c]      = sc;
  a[C1 + c] = bb[c] - mean * sc;
}

// =======================================================================
// MFMA GEMM2: Y2raw = W2 * lrelu(bn1(Y1t^T)); raw fp32 out + BN2 stats
// =======================================================================
__global__ __launch_bounds__(256) void gemm2_kernel(
    const unsigned short* __restrict__ W2b, const unsigned short* __restrict__ Y1t,
    const float* __restrict__ aff, float* __restrict__ out_nf,
    float* __restrict__ stats2)
{
  __shared__ unsigned short As[128][72];
  __shared__ unsigned short Bs[128][72];

  const int tid   = threadIdx.x;
  const int b     = blockIdx.x >> 6;
  const int nbase = (blockIdx.x & 63) * 128;
  const int bm    = blockIdx.y;

  const int sn = tid & 127;
  const int kh = tid >> 7;
  const unsigned short* yrow = Y1t + (size_t)(b * N0 + nbase + sn) * C1;

  const int wv = tid >> 6, lane = tid & 63;
  const int wm = (wv & 1) * 64, wn = (wv >> 1) * 64;
  const int qm = lane & 15, quad = lane >> 4;

  f32x4 acc[4][4];
#pragma unroll
  for (int i = 0; i < 4; ++i)
#pragma unroll
    for (int j = 0; j < 4; ++j) acc[i][j] = (f32x4){0.f, 0.f, 0.f, 0.f};

  for (int kt = 0; kt < C1 / 64; ++kt) {
    __syncthreads();
#pragma unroll
    for (int i = 0; i < 4; ++i) {
      int id = tid + 256 * i;
      int r = id >> 3, ck = id & 7;
      *reinterpret_cast<short8*>(&As[r][ck * 8]) =
          *reinterpret_cast<const short8*>(W2b + (size_t)(bm * 128 + r) * C1 + kt * 64 + ck * 8);
    }
    const int cbase = kt * 64 + kh * 32;
#pragma unroll
    for (int g = 0; g < 4; ++g) {
      alignas(16) unsigned short ye[8];
      *reinterpret_cast<short8*>(ye) =
          *reinterpret_cast<const short8*>(yrow + cbase + g * 8);
      alignas(16) unsigned short tmp[8];
#pragma unroll
      for (int j = 0; j < 8; ++j) {
        int c = cbase + g * 8 + j;
        float v = bu2f(ye[j]) * aff[c] + aff[C1 + c];
        v = (v >= 0.f) ? v : SLOPE * v;
        tmp[j] = f2bu(v);
      }
      *reinterpret_cast<short8*>(&Bs[sn][kh * 32 + g * 8]) =
          *reinterpret_cast<const short8*>(tmp);
    }
    __syncthreads();
#pragma unroll
    for (int h = 0; h < 2; ++h) {
      short8 af[4], bf[4];
#pragma unroll
      for (int i = 0; i < 4; ++i)
        af[i] = *reinterpret_cast<const short8*>(&As[wm + i * 16 + qm][h * 32 + quad * 8]);
#pragma unroll
      for (int j = 0; j < 4; ++j)
        bf[j] = *reinterpret_cast<const short8*>(&Bs[wn + j * 16 + qm][h * 32 + quad * 8]);
#pragma unroll
      for (int i = 0; i < 4; ++i)
#pragma unroll
        for (int j = 0; j < 4; ++j)
          acc[i][j] = __builtin_amdgcn_mfma_f32_16x16x32_bf16(af[i], bf[j], acc[i][j], 0, 0, 0);
    }
  }

  // epilogue: raw fp32 Y2 to out_nf [b][m][N0] + BN2 stats
#pragma unroll
  for (int i = 0; i < 4; ++i) {
    const int mb = bm * 128 + wm + i * 16 + quad * 4;
    float s[4] = {0.f, 0.f, 0.f, 0.f}, s2[4] = {0.f, 0.f, 0.f, 0.f};
#pragma unroll
    for (int j = 0; j < 4; ++j) {
      const int col = nbase + wn + j * 16 + qm;
#pragma unroll
      for (int r = 0; r < 4; ++r) {
        float v = acc[i][j][r];
        out_nf[((size_t)b * C2 + mb + r) * N0 + col] = v;
        s[r] += v; s2[r] += v * v;
      }
    }
#pragma unroll
    for (int m = 1; m < 16; m <<= 1) {
#pragma unroll
      for (int r = 0; r < 4; ++r) { s[r] += __shfl_xor(s[r], m); s2[r] += __shfl_xor(s2[r], m); }
    }
    if (qm == 0) {
#pragma unroll
      for (int r = 0; r < 4; ++r) {
        atomicAdd(&stats2[mb + r], s[r]);
        atomicAdd(&stats2[C2 + mb + r], s2[r]);
      }
    }
  }
}

// ---------------- finalize: in-place BN2 + LeakyReLU on out_nf (fp32) ----------------
__global__ __launch_bounds__(256) void finalize_kernel(float* __restrict__ nf,
                                                       const float* __restrict__ aff)
{
  int id4 = blockIdx.x * 256 + threadIdx.x;      // float4-granule index
  int e = id4 * 4;
  int c = (e % (C2 * N0)) / N0;
  float sc = aff[c], sh = aff[C1 + c];
  float4 v = reinterpret_cast<float4*>(nf)[id4];
  v.x = v.x * sc + sh; v.x = (v.x >= 0.f) ? v.x : SLOPE * v.x;
  v.y = v.y * sc + sh; v.y = (v.y >= 0.f) ? v.y : SLOPE * v.y;
  v.z = v.z * sc + sh; v.z = (v.z >= 0.f) ? v.z : SLOPE * v.z;
  v.w = v.w * sc + sh; v.w = (v.w >= 0.f) ? v.w : SLOPE * v.w;
  reinterpret_cast<float4*>(nf)[id4] = v;
}

// ---------------- copy xyz passthrough (fp32) ----------------
__global__ __launch_bounds__(256) void copy_xyz_kernel(const float* __restrict__ xyz,
                                                       float* __restrict__ out)
{
  int id = blockIdx.x * 256 + threadIdx.x;       // float4 granules, 12288 total
  reinterpret_cast<float4*>(out)[id] = reinterpret_cast<const float4*>(xyz)[id];
}

extern "C" void kernel_launch(void* const* d_in, const int* in_sizes, int n_in,
                              void* d_out, int out_size, void* d_ws, size_t ws_size,
                              hipStream_t stream)
{
  const float* xyz       = (const float*)d_in[0];
  const float* skip      = (const float*)d_in[1];
  const float* xyz_prev  = (const float*)d_in[2];
  const float* feat_prev = (const float*)d_in[3];
  const float* W1        = (const float*)d_in[4];
  const float* g1        = (const float*)d_in[5];
  const float* b1        = (const float*)d_in[6];
  const float* W2        = (const float*)d_in[7];
  const float* g2        = (const float*)d_in[8];
  const float* b2        = (const float*)d_in[9];

  float* out    = (float*)d_out;
  float* out_nf = out + (size_t)B * 3 * N0;      // [B][C2][N0] fp32

  char* ws = (char*)d_ws;
  float*          wq    = (float*)(ws + 0);            // 786432 B
  int*            iq    = (int*)  (ws + 786432);       // 786432 B
  unsigned short* W1b   = (unsigned short*)(ws + 1572864);  // 393216 B
  unsigned short* W2b   = (unsigned short*)(ws + 1966080);  // 131072 B
  float*          stats = (float*)(ws + 2097152);      // 4096 B
  float*          aff   = (float*)(ws + 2101248);      // 4096 B
  unsigned short* Y1t   = (unsigned short*)(ws + 2105344); // [COLS][C1] bf16, 33554432 B
  // total: 35,659,776 B

  prep_kernel<<<768, 256, 0, stream>>>(W1, W2, W1b, W2b, stats);
  knn_kernel<<<dim3(N0 / 256, B), 256, 0, stream>>>(xyz, xyz_prev, wq, iq);
  gemm1_kernel<<<dim3(512, 2), 256, 0, stream>>>(W1b, feat_prev, skip, iq, wq, Y1t, stats);
  affine_kernel<<<1, 256, 0, stream>>>(stats, g1, b1, aff);
  gemm2_kernel<<<dim3(512, 2), 256, 0, stream>>>(W2b, Y1t, aff, out_nf, stats + 512);
  affine_kernel<<<1, 256, 0, stream>>>(stats + 512, g2, b2, aff + 512);
  finalize_kernel<<<(C2 * N0 * B) / (4 * 256), 256, 0, stream>>>(out_nf, aff + 512);
  copy_xyz_kernel<<<(B * 3 * N0) / (4 * 256), 256, 0, stream>>>(xyz, out);
}

// Round 4
// 890.304 us; speedup vs baseline: 1.7309x; 1.1068x over previous
//
#include <hip/hip_runtime.h>
#include <hip/hip_bf16.h>

using bf16 = __hip_bfloat16;

constexpr int B  = 8;
constexpr int N0 = 8192;
constexpr int NS = 2048;
constexpr int CP = 512;
constexpr int CS = 256;
constexpr int C1 = 256;
constexpr int C2 = 256;
constexpr int K1 = CP + CS;          // 768
constexpr int COLS = B * N0;         // 65536
constexpr float BN_EPS = 1e-3f;
constexpr float SLOPE  = 0.01f;

typedef short  short8 __attribute__((ext_vector_type(8)));
typedef float  f32x4  __attribute__((ext_vector_type(4)));

// manual RNE fp32->bf16 (no NaNs in this workload) and back
__device__ __forceinline__ unsigned short f2bu(float f) {
  unsigned int u = __float_as_uint(f);
  return (unsigned short)((u + 0x7fffu + ((u >> 16) & 1u)) >> 16);
}
__device__ __forceinline__ float bu2f(unsigned short v) {
  return __uint_as_float((unsigned int)v << 16);
}

// ---------------- prep: fp32 weights -> bf16 (row-major [M][K]), zero stats ----------------
__global__ __launch_bounds__(256) void prep_kernel(
    const float* __restrict__ W1, const float* __restrict__ W2,
    unsigned short* __restrict__ W1b, unsigned short* __restrict__ W2b,
    float* __restrict__ stats)
{
  int id = blockIdx.x * 256 + threadIdx.x;
  if (id < 1024) stats[id] = 0.0f;
  if (id < C1 * K1) W1b[id] = f2bu(W1[id]);
  if (id < C2 * C1) W2b[id] = f2bu(W2[id]);
}

// ---------------- 3-NN: indices + inverse-distance weights ----------------
__global__ __launch_bounds__(256) void knn_kernel(
    const float* __restrict__ xyz, const float* __restrict__ xyz_prev,
    float* __restrict__ wq, int* __restrict__ iq)
{
#pragma clang fp contract(off)
  __shared__ float4 sp[NS];                       // x,y,z,|p|^2  (32 KB)
  const int b = blockIdx.y;
  const float* xp = xyz_prev + (size_t)b * 3 * NS;
  for (int j = threadIdx.x; j < NS; j += 256) {
    float x = xp[j], y = xp[NS + j], z = xp[2 * NS + j];
    sp[j] = make_float4(x, y, z, (x * x + y * y) + z * z);   // numpy association
  }
  __syncthreads();
  const int n = blockIdx.x * 256 + threadIdx.x;
  const float* xq = xyz + (size_t)b * 3 * N0;
  float qx = xq[n], qy = xq[N0 + n], qz = xq[2 * N0 + n];
  float qq = (qx * qx + qy * qy) + qz * qz;

  float d0 = 1e30f, d1 = 1e30f, d2 = 1e30f;
  int   i0 = 0, i1 = 0, i2 = 0;
  for (int j = 0; j < NS; ++j) {
    float4 p = sp[j];
    float dot = (qx * p.x + qy * p.y) + qz * p.z;
    float d = (qq + p.w) - 2.0f * dot;            // numpy association
    if (d < d0)      { d2 = d1; i2 = i1; d1 = d0; i1 = i0; d0 = d; i0 = j; }
    else if (d < d1) { d2 = d1; i2 = i1; d1 = d;  i1 = j; }
    else if (d < d2) { d2 = d;  i2 = j; }
  }
  d0 = fmaxf(d0, 1e-10f); d1 = fmaxf(d1, 1e-10f); d2 = fmaxf(d2, 1e-10f);
  float v0 = 1.0f / (d0 + 1e-8f), v1 = 1.0f / (d1 + 1e-8f), v2 = 1.0f / (d2 + 1e-8f);
  float s = (v0 + v1) + v2;
  const int gi = (b * N0 + n) * 3;
  wq[gi + 0] = v0 / s; wq[gi + 1] = v1 / s; wq[gi + 2] = v2 / s;
  iq[gi + 0] = i0;     iq[gi + 1] = i1;     iq[gi + 2] = i2;
}

// =======================================================================
// interp: LDS-gather. Block = (b, 16-channel group, n-half).
// Stages 16 feat rows (16x2048 bf16 = 64 KB LDS), gathers per query from
// LDS, writes Xt[n][k] (k-major) 32 B per query-channelgroup.
// =======================================================================
__global__ __launch_bounds__(256) void interp_kernel(
    const float* __restrict__ feat_prev, const int* __restrict__ iq,
    const float* __restrict__ wq, unsigned short* __restrict__ Xt)
{
  __shared__ unsigned short sf[16 * 2048];        // 64 KB
  const int bx = blockIdx.x;                      // 512 blocks
  const int b  = bx >> 6;                         // 8
  const int cg = (bx >> 1) & 31;                  // 32 channel groups
  const int nh = bx & 1;                          // n-half
  const int c0 = cg * 16;
  const float* fp = feat_prev + ((size_t)b * CP + c0) * NS;

  // stage 16 rows: 32768 floats = 8192 float4
  for (int id = threadIdx.x; id < 8192; id += 256) {
    float4 v = reinterpret_cast<const float4*>(fp)[id];
    ushort4 o;
    o.x = f2bu(v.x); o.y = f2bu(v.y); o.z = f2bu(v.z); o.w = f2bu(v.w);
    *reinterpret_cast<ushort4*>(&sf[id * 4]) = o;
  }
  __syncthreads();

  const int nbase = nh * 4096;
  for (int it = 0; it < 16; ++it) {
    const int n    = nbase + it * 256 + threadIdx.x;
    const int gcol = b * N0 + n;
    const int gq   = gcol * 3;
    const int i0 = iq[gq], i1 = iq[gq + 1], i2 = iq[gq + 2];
    const float w0 = wq[gq], w1 = wq[gq + 1], w2 = wq[gq + 2];
    unsigned short outv[16];
#pragma unroll
    for (int c = 0; c < 16; ++c) {
      const unsigned short* row = &sf[c * 2048];
      float v = w0 * bu2f(row[i0]) + w1 * bu2f(row[i1]) + w2 * bu2f(row[i2]);
      outv[c] = f2bu(v);
    }
    unsigned short* dst = Xt + (size_t)gcol * K1 + c0;
    *reinterpret_cast<short8*>(dst)     = *reinterpret_cast<short8*>(&outv[0]);
    *reinterpret_cast<short8*>(dst + 8) = *reinterpret_cast<short8*>(&outv[8]);
  }
}

// =======================================================================
// skipT: transpose skip fp32 [c][n] -> Xt[n][512+c] bf16. Tile 64x64.
// =======================================================================
__global__ __launch_bounds__(256) void skipt_kernel(
    const float* __restrict__ skip, unsigned short* __restrict__ Xt)
{
  __shared__ float T[64][65];
  const int kt   = blockIdx.x & 3;               // 4 k-tiles of 64
  const int ct   = blockIdx.x >> 2;              // 1024 col-tiles of 64
  const int col0 = ct * 64;
  const int b    = col0 >> 13;
  const int n0   = col0 & 8191;
  const float* src = skip + ((size_t)b * CS + kt * 64) * N0 + n0;

  for (int id = threadIdx.x; id < 1024; id += 256) {
    int r = id >> 4, q = id & 15;
    float4 v = *reinterpret_cast<const float4*>(src + (size_t)r * N0 + q * 4);
    T[r][q * 4 + 0] = v.x; T[r][q * 4 + 1] = v.y;
    T[r][q * 4 + 2] = v.z; T[r][q * 4 + 3] = v.w;
  }
  __syncthreads();
  for (int id = threadIdx.x; id < 512; id += 256) {
    int n = id >> 3, q = id & 7;
    alignas(16) unsigned short tmp[8];
#pragma unroll
    for (int j = 0; j < 8; ++j) tmp[j] = f2bu(T[q * 8 + j][n]);
    *reinterpret_cast<short8*>(Xt + (size_t)(col0 + n) * K1 + CP + kt * 64 + q * 8) =
        *reinterpret_cast<short8*>(tmp);
  }
}

// =======================================================================
// MFMA GEMM1: Y1t[n][c1] = (W1 * Xt^T)^T  + BN1 stats   (clean stream GEMM)
// grid (512, 2): x -> col-tile of 128, y -> bm (M-half)
// =======================================================================
__global__ __launch_bounds__(256) void gemm1_kernel(
    const unsigned short* __restrict__ W1b, const unsigned short* __restrict__ Xt,
    unsigned short* __restrict__ Y1t, float* __restrict__ stats)
{
  __shared__ unsigned short As[128][72];   // [m][k], 144 B rows (16-mult)
  __shared__ unsigned short Bs[128][72];   // [n][k]

  const int tid   = threadIdx.x;
  const int gcol0 = blockIdx.x * 128;
  const int bm    = blockIdx.y;

  const int wv = tid >> 6, lane = tid & 63;
  const int wm = (wv & 1) * 64, wn = (wv >> 1) * 64;
  const int qm = lane & 15, quad = lane >> 4;

  f32x4 acc[4][4];
#pragma unroll
  for (int i = 0; i < 4; ++i)
#pragma unroll
    for (int j = 0; j < 4; ++j) acc[i][j] = (f32x4){0.f, 0.f, 0.f, 0.f};

  for (int kt = 0; kt < K1 / 64; ++kt) {
    __syncthreads();
#pragma unroll
    for (int i = 0; i < 4; ++i) {
      int id = tid + 256 * i;              // 1024 16B-chunks
      int r = id >> 3, ck = id & 7;
      *reinterpret_cast<short8*>(&As[r][ck * 8]) =
          *reinterpret_cast<const short8*>(W1b + (size_t)(bm * 128 + r) * K1 + kt * 64 + ck * 8);
    }
#pragma unroll
    for (int i = 0; i < 4; ++i) {
      int id = tid + 256 * i;
      int n = id >> 3, ck = id & 7;        // 8 lanes cover one n-row's 128 B
      *reinterpret_cast<short8*>(&Bs[n][ck * 8]) =
          *reinterpret_cast<const short8*>(Xt + (size_t)(gcol0 + n) * K1 + kt * 64 + ck * 8);
    }
    __syncthreads();
#pragma unroll
    for (int h = 0; h < 2; ++h) {
      short8 af[4], bf[4];
#pragma unroll
      for (int i = 0; i < 4; ++i)
        af[i] = *reinterpret_cast<const short8*>(&As[wm + i * 16 + qm][h * 32 + quad * 8]);
#pragma unroll
      for (int j = 0; j < 4; ++j)
        bf[j] = *reinterpret_cast<const short8*>(&Bs[wn + j * 16 + qm][h * 32 + quad * 8]);
#pragma unroll
      for (int i = 0; i < 4; ++i)
#pragma unroll
        for (int j = 0; j < 4; ++j)
          acc[i][j] = __builtin_amdgcn_mfma_f32_16x16x32_bf16(af[i], bf[j], acc[i][j], 0, 0, 0);
    }
  }

  // epilogue: Y1t[n][c] bf16 (8 B contiguous) + BN1 stats
#pragma unroll
  for (int i = 0; i < 4; ++i) {
    const int mb = bm * 128 + wm + i * 16 + quad * 4;
    float s[4] = {0.f, 0.f, 0.f, 0.f}, s2[4] = {0.f, 0.f, 0.f, 0.f};
#pragma unroll
    for (int j = 0; j < 4; ++j) {
      const int gc = gcol0 + wn + j * 16 + qm;
      ushort4 o;
      o.x = f2bu(acc[i][j][0]); o.y = f2bu(acc[i][j][1]);
      o.z = f2bu(acc[i][j][2]); o.w = f2bu(acc[i][j][3]);
      *reinterpret_cast<ushort4*>(Y1t + (size_t)gc * C1 + mb) = o;
#pragma unroll
      for (int r = 0; r < 4; ++r) {
        float v = acc[i][j][r];
        s[r] += v; s2[r] += v * v;
      }
    }
#pragma unroll
    for (int m = 1; m < 16; m <<= 1) {
#pragma unroll
      for (int r = 0; r < 4; ++r) { s[r] += __shfl_xor(s[r], m); s2[r] += __shfl_xor(s2[r], m); }
    }
    if (qm == 0) {
#pragma unroll
      for (int r = 0; r < 4; ++r) {
        atomicAdd(&stats[mb + r], s[r]);
        atomicAdd(&stats[C1 + mb + r], s2[r]);
      }
    }
  }
}

// ---------------- affine: fold BN stats + gamma/beta into scale/shift ----------------
__global__ __launch_bounds__(256) void affine_kernel(
    const float* __restrict__ s, const float* __restrict__ g,
    const float* __restrict__ bb, float* __restrict__ a)
{
  int c = threadIdx.x;
  float inv = 1.0f / (float)COLS;
  float mean = s[c] * inv;
  float var  = s[C1 + c] * inv - mean * mean;
  float sc   = g[c] / sqrtf(var + BN_EPS);
  a[c]      = sc;
  a[C1 + c] = bb[c] - mean * sc;
}

// =======================================================================
// MFMA GEMM2: Y2raw = W2 * lrelu(bn1(Y1t^T)); raw fp32 out + BN2 stats
// Coalesced B-staging: 8 lanes cover one n-row's 128 B chunk.
// =======================================================================
__global__ __launch_bounds__(256) void gemm2_kernel(
    const unsigned short* __restrict__ W2b, const unsigned short* __restrict__ Y1t,
    const float* __restrict__ aff, float* __restrict__ out_nf,
    float* __restrict__ stats2)
{
  __shared__ unsigned short As[128][72];
  __shared__ unsigned short Bs[128][72];

  const int tid   = threadIdx.x;
  const int gcol0 = blockIdx.x * 128;
  const int bm    = blockIdx.y;
  const int b     = gcol0 >> 13;
  const int ncol0 = gcol0 & 8191;

  const int wv = tid >> 6, lane = tid & 63;
  const int wm = (wv & 1) * 64, wn = (wv >> 1) * 64;
  const int qm = lane & 15, quad = lane >> 4;

  f32x4 acc[4][4];
#pragma unroll
  for (int i = 0; i < 4; ++i)
#pragma unroll
    for (int j = 0; j < 4; ++j) acc[i][j] = (f32x4){0.f, 0.f, 0.f, 0.f};

  for (int kt = 0; kt < C1 / 64; ++kt) {
    __syncthreads();
#pragma unroll
    for (int i = 0; i < 4; ++i) {
      int id = tid + 256 * i;
      int r = id >> 3, ck = id & 7;
      *reinterpret_cast<short8*>(&As[r][ck * 8]) =
          *reinterpret_cast<const short8*>(W2b + (size_t)(bm * 128 + r) * C1 + kt * 64 + ck * 8);
    }
#pragma unroll
    for (int i = 0; i < 4; ++i) {
      int id = tid + 256 * i;
      int n = id >> 3, ck = id & 7;
      const int c0 = kt * 64 + ck * 8;
      alignas(16) unsigned short ye[8];
      *reinterpret_cast<short8*>(ye) =
          *reinterpret_cast<const short8*>(Y1t + (size_t)(gcol0 + n) * C1 + c0);
      float4 sc0 = *reinterpret_cast<const float4*>(aff + c0);
      float4 sc1 = *reinterpret_cast<const float4*>(aff + c0 + 4);
      float4 sh0 = *reinterpret_cast<const float4*>(aff + C1 + c0);
      float4 sh1 = *reinterpret_cast<const float4*>(aff + C1 + c0 + 4);
      alignas(16) unsigned short tmp[8];
      const float* scp = &sc0.x; const float* shp = &sh0.x;
#pragma unroll
      for (int j = 0; j < 4; ++j) {
        float v = bu2f(ye[j]) * (&sc0.x)[j] + (&sh0.x)[j];
        v = (v >= 0.f) ? v : SLOPE * v;
        tmp[j] = f2bu(v);
      }
#pragma unroll
      for (int j = 0; j < 4; ++j) {
        float v = bu2f(ye[4 + j]) * (&sc1.x)[j] + (&sh1.x)[j];
        v = (v >= 0.f) ? v : SLOPE * v;
        tmp[4 + j] = f2bu(v);
      }
      (void)scp; (void)shp;
      *reinterpret_cast<short8*>(&Bs[n][ck * 8]) = *reinterpret_cast<short8*>(tmp);
    }
    __syncthreads();
#pragma unroll
    for (int h = 0; h < 2; ++h) {
      short8 af[4], bf[4];
#pragma unroll
      for (int i = 0; i < 4; ++i)
        af[i] = *reinterpret_cast<const short8*>(&As[wm + i * 16 + qm][h * 32 + quad * 8]);
#pragma unroll
      for (int j = 0; j < 4; ++j)
        bf[j] = *reinterpret_cast<const short8*>(&Bs[wn + j * 16 + qm][h * 32 + quad * 8]);
#pragma unroll
      for (int i = 0; i < 4; ++i)
#pragma unroll
        for (int j = 0; j < 4; ++j)
          acc[i][j] = __builtin_amdgcn_mfma_f32_16x16x32_bf16(af[i], bf[j], acc[i][j], 0, 0, 0);
    }
  }

  // epilogue: raw fp32 Y2 to out_nf [b][m][N0] + BN2 stats
#pragma unroll
  for (int i = 0; i < 4; ++i) {
    const int mb = bm * 128 + wm + i * 16 + quad * 4;
    float s[4] = {0.f, 0.f, 0.f, 0.f}, s2[4] = {0.f, 0.f, 0.f, 0.f};
#pragma unroll
    for (int j = 0; j < 4; ++j) {
      const int col = ncol0 + wn + j * 16 + qm;
#pragma unroll
      for (int r = 0; r < 4; ++r) {
        float v = acc[i][j][r];
        out_nf[((size_t)b * C2 + mb + r) * N0 + col] = v;
        s[r] += v; s2[r] += v * v;
      }
    }
#pragma unroll
    for (int m = 1; m < 16; m <<= 1) {
#pragma unroll
      for (int r = 0; r < 4; ++r) { s[r] += __shfl_xor(s[r], m); s2[r] += __shfl_xor(s2[r], m); }
    }
    if (qm == 0) {
#pragma unroll
      for (int r = 0; r < 4; ++r) {
        atomicAdd(&stats2[mb + r], s[r]);
        atomicAdd(&stats2[C2 + mb + r], s2[r]);
      }
    }
  }
}

// ---------------- finalize: in-place BN2 + LeakyReLU on out_nf (fp32) ----------------
__global__ __launch_bounds__(256) void finalize_kernel(float* __restrict__ nf,
                                                       const float* __restrict__ aff)
{
  int id4 = blockIdx.x * 256 + threadIdx.x;      // float4-granule index
  int e = id4 * 4;
  int c = (e % (C2 * N0)) / N0;
  float sc = aff[c], sh = aff[C1 + c];
  float4 v = reinterpret_cast<float4*>(nf)[id4];
  v.x = v.x * sc + sh; v.x = (v.x >= 0.f) ? v.x : SLOPE * v.x;
  v.y = v.y * sc + sh; v.y = (v.y >= 0.f) ? v.y : SLOPE * v.y;
  v.z = v.z * sc + sh; v.z = (v.z >= 0.f) ? v.z : SLOPE * v.z;
  v.w = v.w * sc + sh; v.w = (v.w >= 0.f) ? v.w : SLOPE * v.w;
  reinterpret_cast<float4*>(nf)[id4] = v;
}

// ---------------- copy xyz passthrough (fp32) ----------------
__global__ __launch_bounds__(256) void copy_xyz_kernel(const float* __restrict__ xyz,
                                                       float* __restrict__ out)
{
  int id = blockIdx.x * 256 + threadIdx.x;       // float4 granules, 12288 total
  reinterpret_cast<float4*>(out)[id] = reinterpret_cast<const float4*>(xyz)[id];
}

extern "C" void kernel_launch(void* const* d_in, const int* in_sizes, int n_in,
                              void* d_out, int out_size, void* d_ws, size_t ws_size,
                              hipStream_t stream)
{
  const float* xyz       = (const float*)d_in[0];
  const float* skip      = (const float*)d_in[1];
  const float* xyz_prev  = (const float*)d_in[2];
  const float* feat_prev = (const float*)d_in[3];
  const float* W1        = (const float*)d_in[4];
  const float* g1        = (const float*)d_in[5];
  const float* b1        = (const float*)d_in[6];
  const float* W2        = (const float*)d_in[7];
  const float* g2        = (const float*)d_in[8];
  const float* b2        = (const float*)d_in[9];

  float* out    = (float*)d_out;
  float* out_nf = out + (size_t)B * 3 * N0;      // [B][C2][N0] fp32

  char* ws = (char*)d_ws;
  float*          wq    = (float*)(ws + 0);                 //   786432 B
  int*            iq    = (int*)  (ws + 786432);            //   786432 B
  unsigned short* W1b   = (unsigned short*)(ws + 1572864);  //   393216 B
  unsigned short* W2b   = (unsigned short*)(ws + 1966080);  //   131072 B
  float*          stats = (float*)(ws + 2097152);           //     4096 B
  float*          aff   = (float*)(ws + 2101248);           //     4096 B
  unsigned short* Y1t   = (unsigned short*)(ws + 2105344);  // 33554432 B  [COLS][C1]
  unsigned short* Xt    = (unsigned short*)(ws + 35659776); // 100663296 B [COLS][K1]
  // total: 136,323,072 B

  prep_kernel<<<768, 256, 0, stream>>>(W1, W2, W1b, W2b, stats);
  knn_kernel<<<dim3(N0 / 256, B), 256, 0, stream>>>(xyz, xyz_prev, wq, iq);
  interp_kernel<<<512, 256, 0, stream>>>(feat_prev, iq, wq, Xt);
  skipt_kernel<<<4096, 256, 0, stream>>>(skip, Xt);
  gemm1_kernel<<<dim3(512, 2), 256, 0, stream>>>(W1b, Xt, Y1t, stats);
  affine_kernel<<<1, 256, 0, stream>>>(stats, g1, b1, aff);
  gemm2_kernel<<<dim3(512, 2), 256, 0, stream>>>(W2b, Y1t, aff, out_nf, stats + 512);
  affine_kernel<<<1, 256, 0, stream>>>(stats + 512, g2, b2, aff + 512);
  finalize_kernel<<<(C2 * N0 * B) / (4 * 256), 256, 0, stream>>>(out_nf, aff + 512);
  copy_xyz_kernel<<<(B * 3 * N0) / (4 * 256), 256, 0, stream>>>(xyz, out);
}

// Round 5
// 742.843 us; speedup vs baseline: 2.0745x; 1.1985x over previous
//
#include <hip/hip_runtime.h>
#include <hip/hip_bf16.h>

using bf16 = __hip_bfloat16;

constexpr int B  = 8;
constexpr int N0 = 8192;
constexpr int NS = 2048;
constexpr int CP = 512;
constexpr int CS = 256;
constexpr int C1 = 256;
constexpr int C2 = 256;
constexpr int K1 = CP + CS;          // 768
constexpr int COLS = B * N0;         // 65536
constexpr float BN_EPS = 1e-3f;
constexpr float SLOPE  = 0.01f;

typedef short  short8 __attribute__((ext_vector_type(8)));
typedef float  f32x4  __attribute__((ext_vector_type(4)));

// manual RNE fp32->bf16 (no NaNs in this workload) and back
__device__ __forceinline__ unsigned short f2bu(float f) {
  unsigned int u = __float_as_uint(f);
  return (unsigned short)((u + 0x7fffu + ((u >> 16) & 1u)) >> 16);
}
__device__ __forceinline__ float bu2f(unsigned short v) {
  return __uint_as_float((unsigned int)v << 16);
}

// ---------------- prep: fp32 weights -> bf16 (row-major [M][K]), zero stats ----------------
__global__ __launch_bounds__(256) void prep_kernel(
    const float* __restrict__ W1, const float* __restrict__ W2,
    unsigned short* __restrict__ W1b, unsigned short* __restrict__ W2b,
    float* __restrict__ stats)
{
  int id = blockIdx.x * 256 + threadIdx.x;
  if (id < 1024) stats[id] = 0.0f;
  if (id < C1 * K1) W1b[id] = f2bu(W1[id]);
  if (id < C2 * C1) W2b[id] = f2bu(W2[id]);
}

// =======================================================================
// 3-NN, slice-split: block = 64 queries x 4 slices (256 thr).
// Each thread scans 512 source points -> local top-3; stable LDS merge.
// Grid (128, 8) = 1024 blocks -> 4 blocks/CU, 16 waves/CU.
// =======================================================================
__global__ __launch_bounds__(256) void knn_kernel(
    const float* __restrict__ xyz, const float* __restrict__ xyz_prev,
    float* __restrict__ wq, int* __restrict__ iq)
{
#pragma clang fp contract(off)
  __shared__ float4 sp[NS];                 // x,y,z,|p|^2  (32 KB)
  __shared__ float  md[4][64][3];           // per-slice top-3 dists (3 KB)
  __shared__ int    mi[4][64][3];           // per-slice top-3 idx   (3 KB)
  const int b = blockIdx.y;
  const float* xp = xyz_prev + (size_t)b * 3 * NS;
  for (int j = threadIdx.x; j < NS; j += 256) {
    float x = xp[j], y = xp[NS + j], z = xp[2 * NS + j];
    sp[j] = make_float4(x, y, z, (x * x + y * y) + z * z);   // numpy association
  }
  __syncthreads();

  const int q  = threadIdx.x & 63;          // query within block (lane id)
  const int sl = threadIdx.x >> 6;          // slice = wave id
  const int n  = blockIdx.x * 64 + q;
  const float* xq = xyz + (size_t)b * 3 * N0;
  float qx = xq[n], qy = xq[N0 + n], qz = xq[2 * N0 + n];
  float qq = (qx * qx + qy * qy) + qz * qz;

  float d0 = 1e30f, d1 = 1e30f, d2 = 1e30f;
  int   i0 = 0, i1 = 0, i2 = 0;
  const int j0 = sl * (NS / 4), j1 = j0 + (NS / 4);
#pragma unroll 4
  for (int j = j0; j < j1; ++j) {
    float4 p = sp[j];
    float dot = (qx * p.x + qy * p.y) + qz * p.z;
    float d = (qq + p.w) - 2.0f * dot;      // numpy association
    if (d < d0)      { d2 = d1; i2 = i1; d1 = d0; i1 = i0; d0 = d; i0 = j; }
    else if (d < d1) { d2 = d1; i2 = i1; d1 = d;  i1 = j; }
    else if (d < d2) { d2 = d;  i2 = j; }
  }
  md[sl][q][0] = d0; md[sl][q][1] = d1; md[sl][q][2] = d2;
  mi[sl][q][0] = i0; mi[sl][q][1] = i1; mi[sl][q][2] = i2;
  __syncthreads();

  if (threadIdx.x < 64) {
    // stable merge: slices in ascending-j order, strict < keeps lowest index on ties
    float e0 = 1e30f, e1 = 1e30f, e2 = 1e30f;
    int   k0 = 0, k1 = 0, k2 = 0;
#pragma unroll
    for (int s = 0; s < 4; ++s) {
#pragma unroll
      for (int t = 0; t < 3; ++t) {
        float d = md[s][q][t]; int ii = mi[s][q][t];
        if (d < e0)      { e2 = e1; k2 = k1; e1 = e0; k1 = k0; e0 = d; k0 = ii; }
        else if (d < e1) { e2 = e1; k2 = k1; e1 = d;  k1 = ii; }
        else if (d < e2) { e2 = d;  k2 = ii; }
      }
    }
    e0 = fmaxf(e0, 1e-10f); e1 = fmaxf(e1, 1e-10f); e2 = fmaxf(e2, 1e-10f);
    float v0 = 1.0f / (e0 + 1e-8f), v1 = 1.0f / (e1 + 1e-8f), v2 = 1.0f / (e2 + 1e-8f);
    float s = (v0 + v1) + v2;
    const int gi = (b * N0 + n) * 3;
    wq[gi + 0] = v0 / s; wq[gi + 1] = v1 / s; wq[gi + 2] = v2 / s;
    iq[gi + 0] = k0;     iq[gi + 1] = k1;     iq[gi + 2] = k2;
  }
}

// =======================================================================
// interp: LDS-gather. Block = (b, 16-channel group, n-half).
// Stages 16 feat rows (16x2048 bf16 = 64 KB LDS), gathers per query from
// LDS, writes Xt[n][k] (k-major) 32 B per query-channelgroup.
// =======================================================================
__global__ __launch_bounds__(256) void interp_kernel(
    const float* __restrict__ feat_prev, const int* __restrict__ iq,
    const float* __restrict__ wq, unsigned short* __restrict__ Xt)
{
  __shared__ unsigned short sf[16 * 2048];        // 64 KB
  const int bx = blockIdx.x;                      // 512 blocks
  const int b  = bx >> 6;                         // 8
  const int cg = (bx >> 1) & 31;                  // 32 channel groups
  const int nh = bx & 1;                          // n-half
  const int c0 = cg * 16;
  const float* fp = feat_prev + ((size_t)b * CP + c0) * NS;

  // stage 16 rows: 32768 floats = 8192 float4
  for (int id = threadIdx.x; id < 8192; id += 256) {
    float4 v = reinterpret_cast<const float4*>(fp)[id];
    ushort4 o;
    o.x = f2bu(v.x); o.y = f2bu(v.y); o.z = f2bu(v.z); o.w = f2bu(v.w);
    *reinterpret_cast<ushort4*>(&sf[id * 4]) = o;
  }
  __syncthreads();

  const int nbase = nh * 4096;
  for (int it = 0; it < 16; ++it) {
    const int n    = nbase + it * 256 + threadIdx.x;
    const int gcol = b * N0 + n;
    const int gq   = gcol * 3;
    const int i0 = iq[gq], i1 = iq[gq + 1], i2 = iq[gq + 2];
    const float w0 = wq[gq], w1 = wq[gq + 1], w2 = wq[gq + 2];
    unsigned short outv[16];
#pragma unroll
    for (int c = 0; c < 16; ++c) {
      const unsigned short* row = &sf[c * 2048];
      float v = w0 * bu2f(row[i0]) + w1 * bu2f(row[i1]) + w2 * bu2f(row[i2]);
      outv[c] = f2bu(v);
    }
    unsigned short* dst = Xt + (size_t)gcol * K1 + c0;
    *reinterpret_cast<short8*>(dst)     = *reinterpret_cast<short8*>(&outv[0]);
    *reinterpret_cast<short8*>(dst + 8) = *reinterpret_cast<short8*>(&outv[8]);
  }
}

// =======================================================================
// skipT: transpose skip fp32 [c][n] -> Xt[n][512+c] bf16. Tile 64x64.
// =======================================================================
__global__ __launch_bounds__(256) void skipt_kernel(
    const float* __restrict__ skip, unsigned short* __restrict__ Xt)
{
  __shared__ float T[64][65];
  const int kt   = blockIdx.x & 3;               // 4 k-tiles of 64
  const int ct   = blockIdx.x >> 2;              // 1024 col-tiles of 64
  const int col0 = ct * 64;
  const int b    = col0 >> 13;
  const int n0   = col0 & 8191;
  const float* src = skip + ((size_t)b * CS + kt * 64) * N0 + n0;

  for (int id = threadIdx.x; id < 1024; id += 256) {
    int r = id >> 4, q = id & 15;
    float4 v = *reinterpret_cast<const float4*>(src + (size_t)r * N0 + q * 4);
    T[r][q * 4 + 0] = v.x; T[r][q * 4 + 1] = v.y;
    T[r][q * 4 + 2] = v.z; T[r][q * 4 + 3] = v.w;
  }
  __syncthreads();
  for (int id = threadIdx.x; id < 512; id += 256) {
    int n = id >> 3, q = id & 7;
    alignas(16) unsigned short tmp[8];
#pragma unroll
    for (int j = 0; j < 8; ++j) tmp[j] = f2bu(T[q * 8 + j][n]);
    *reinterpret_cast<short8*>(Xt + (size_t)(col0 + n) * K1 + CP + kt * 64 + q * 8) =
        *reinterpret_cast<short8*>(tmp);
  }
}

// =======================================================================
// MFMA GEMM1: Y1t[n][c1] = (W1 * Xt^T)^T  + BN1 stats   (clean stream GEMM)
// grid (512, 2): x -> col-tile of 128, y -> bm (M-half)
// =======================================================================
__global__ __launch_bounds__(256) void gemm1_kernel(
    const unsigned short* __restrict__ W1b, const unsigned short* __restrict__ Xt,
    unsigned short* __restrict__ Y1t, float* __restrict__ stats)
{
  __shared__ unsigned short As[128][72];   // [m][k], 144 B rows (16-mult)
  __shared__ unsigned short Bs[128][72];   // [n][k]

  const int tid   = threadIdx.x;
  const int gcol0 = blockIdx.x * 128;
  const int bm    = blockIdx.y;

  const int wv = tid >> 6, lane = tid & 63;
  const int wm = (wv & 1) * 64, wn = (wv >> 1) * 64;
  const int qm = lane & 15, quad = lane >> 4;

  f32x4 acc[4][4];
#pragma unroll
  for (int i = 0; i < 4; ++i)
#pragma unroll
    for (int j = 0; j < 4; ++j) acc[i][j] = (f32x4){0.f, 0.f, 0.f, 0.f};

  for (int kt = 0; kt < K1 / 64; ++kt) {
    __syncthreads();
#pragma unroll
    for (int i = 0; i < 4; ++i) {
      int id = tid + 256 * i;              // 1024 16B-chunks
      int r = id >> 3, ck = id & 7;
      *reinterpret_cast<short8*>(&As[r][ck * 8]) =
          *reinterpret_cast<const short8*>(W1b + (size_t)(bm * 128 + r) * K1 + kt * 64 + ck * 8);
    }
#pragma unroll
    for (int i = 0; i < 4; ++i) {
      int id = tid + 256 * i;
      int n = id >> 3, ck = id & 7;        // 8 lanes cover one n-row's 128 B
      *reinterpret_cast<short8*>(&Bs[n][ck * 8]) =
          *reinterpret_cast<const short8*>(Xt + (size_t)(gcol0 + n) * K1 + kt * 64 + ck * 8);
    }
    __syncthreads();
#pragma unroll
    for (int h = 0; h < 2; ++h) {
      short8 af[4], bf[4];
#pragma unroll
      for (int i = 0; i < 4; ++i)
        af[i] = *reinterpret_cast<const short8*>(&As[wm + i * 16 + qm][h * 32 + quad * 8]);
#pragma unroll
      for (int j = 0; j < 4; ++j)
        bf[j] = *reinterpret_cast<const short8*>(&Bs[wn + j * 16 + qm][h * 32 + quad * 8]);
#pragma unroll
      for (int i = 0; i < 4; ++i)
#pragma unroll
        for (int j = 0; j < 4; ++j)
          acc[i][j] = __builtin_amdgcn_mfma_f32_16x16x32_bf16(af[i], bf[j], acc[i][j], 0, 0, 0);
    }
  }

  // epilogue: Y1t[n][c] bf16 (8 B contiguous) + BN1 stats
#pragma unroll
  for (int i = 0; i < 4; ++i) {
    const int mb = bm * 128 + wm + i * 16 + quad * 4;
    float s[4] = {0.f, 0.f, 0.f, 0.f}, s2[4] = {0.f, 0.f, 0.f, 0.f};
#pragma unroll
    for (int j = 0; j < 4; ++j) {
      const int gc = gcol0 + wn + j * 16 + qm;
      ushort4 o;
      o.x = f2bu(acc[i][j][0]); o.y = f2bu(acc[i][j][1]);
      o.z = f2bu(acc[i][j][2]); o.w = f2bu(acc[i][j][3]);
      *reinterpret_cast<ushort4*>(Y1t + (size_t)gc * C1 + mb) = o;
#pragma unroll
      for (int r = 0; r < 4; ++r) {
        float v = acc[i][j][r];
        s[r] += v; s2[r] += v * v;
      }
    }
#pragma unroll
    for (int m = 1; m < 16; m <<= 1) {
#pragma unroll
      for (int r = 0; r < 4; ++r) { s[r] += __shfl_xor(s[r], m); s2[r] += __shfl_xor(s2[r], m); }
    }
    if (qm == 0) {
#pragma unroll
      for (int r = 0; r < 4; ++r) {
        atomicAdd(&stats[mb + r], s[r]);
        atomicAdd(&stats[C1 + mb + r], s2[r]);
      }
    }
  }
}

// ---------------- affine: fold BN stats + gamma/beta into scale/shift ----------------
__global__ __launch_bounds__(256) void affine_kernel(
    const float* __restrict__ s, const float* __restrict__ g,
    const float* __restrict__ bb, float* __restrict__ a)
{
  int c = threadIdx.x;
  float inv = 1.0f / (float)COLS;
  float mean = s[c] * inv;
  float var  = s[C1 + c] * inv - mean * mean;
  float sc   = g[c] / sqrtf(var + BN_EPS);
  a[c]      = sc;
  a[C1 + c] = bb[c] - mean * sc;
}

// =======================================================================
// MFMA GEMM2: Y2raw = W2 * lrelu(bn1(Y1t^T)); raw fp32 out + BN2 stats
// Coalesced B-staging: 8 lanes cover one n-row's 128 B chunk.
// =======================================================================
__global__ __launch_bounds__(256) void gemm2_kernel(
    const unsigned short* __restrict__ W2b, const unsigned short* __restrict__ Y1t,
    const float* __restrict__ aff, float* __restrict__ out_nf,
    float* __restrict__ stats2)
{
  __shared__ unsigned short As[128][72];
  __shared__ unsigned short Bs[128][72];

  const int tid   = threadIdx.x;
  const int gcol0 = blockIdx.x * 128;
  const int bm    = blockIdx.y;
  const int b     = gcol0 >> 13;
  const int ncol0 = gcol0 & 8191;

  const int wv = tid >> 6, lane = tid & 63;
  const int wm = (wv & 1) * 64, wn = (wv >> 1) * 64;
  const int qm = lane & 15, quad = lane >> 4;

  f32x4 acc[4][4];
#pragma unroll
  for (int i = 0; i < 4; ++i)
#pragma unroll
    for (int j = 0; j < 4; ++j) acc[i][j] = (f32x4){0.f, 0.f, 0.f, 0.f};

  for (int kt = 0; kt < C1 / 64; ++kt) {
    __syncthreads();
#pragma unroll
    for (int i = 0; i < 4; ++i) {
      int id = tid + 256 * i;
      int r = id >> 3, ck = id & 7;
      *reinterpret_cast<short8*>(&As[r][ck * 8]) =
          *reinterpret_cast<const short8*>(W2b + (size_t)(bm * 128 + r) * C1 + kt * 64 + ck * 8);
    }
#pragma unroll
    for (int i = 0; i < 4; ++i) {
      int id = tid + 256 * i;
      int n = id >> 3, ck = id & 7;
      const int c0 = kt * 64 + ck * 8;
      alignas(16) unsigned short ye[8];
      *reinterpret_cast<short8*>(ye) =
          *reinterpret_cast<const short8*>(Y1t + (size_t)(gcol0 + n) * C1 + c0);
      float4 sc0 = *reinterpret_cast<const float4*>(aff + c0);
      float4 sc1 = *reinterpret_cast<const float4*>(aff + c0 + 4);
      float4 sh0 = *reinterpret_cast<const float4*>(aff + C1 + c0);
      float4 sh1 = *reinterpret_cast<const float4*>(aff + C1 + c0 + 4);
      alignas(16) unsigned short tmp[8];
#pragma unroll
      for (int j = 0; j < 4; ++j) {
        float v = bu2f(ye[j]) * (&sc0.x)[j] + (&sh0.x)[j];
        v = (v >= 0.f) ? v : SLOPE * v;
        tmp[j] = f2bu(v);
      }
#pragma unroll
      for (int j = 0; j < 4; ++j) {
        float v = bu2f(ye[4 + j]) * (&sc1.x)[j] + (&sh1.x)[j];
        v = (v >= 0.f) ? v : SLOPE * v;
        tmp[4 + j] = f2bu(v);
      }
      *reinterpret_cast<short8*>(&Bs[n][ck * 8]) = *reinterpret_cast<short8*>(tmp);
    }
    __syncthreads();
#pragma unroll
    for (int h = 0; h < 2; ++h) {
      short8 af[4], bf[4];
#pragma unroll
      for (int i = 0; i < 4; ++i)
        af[i] = *reinterpret_cast<const short8*>(&As[wm + i * 16 + qm][h * 32 + quad * 8]);
#pragma unroll
      for (int j = 0; j < 4; ++j)
        bf[j] = *reinterpret_cast<const short8*>(&Bs[wn + j * 16 + qm][h * 32 + quad * 8]);
#pragma unroll
      for (int i = 0; i < 4; ++i)
#pragma unroll
        for (int j = 0; j < 4; ++j)
          acc[i][j] = __builtin_amdgcn_mfma_f32_16x16x32_bf16(af[i], bf[j], acc[i][j], 0, 0, 0);
    }
  }

  // epilogue: raw fp32 Y2 to out_nf [b][m][N0] + BN2 stats
#pragma unroll
  for (int i = 0; i < 4; ++i) {
    const int mb = bm * 128 + wm + i * 16 + quad * 4;
    float s[4] = {0.f, 0.f, 0.f, 0.f}, s2[4] = {0.f, 0.f, 0.f, 0.f};
#pragma unroll
    for (int j = 0; j < 4; ++j) {
      const int col = ncol0 + wn + j * 16 + qm;
#pragma unroll
      for (int r = 0; r < 4; ++r) {
        float v = acc[i][j][r];
        out_nf[((size_t)b * C2 + mb + r) * N0 + col] = v;
        s[r] += v; s2[r] += v * v;
      }
    }
#pragma unroll
    for (int m = 1; m < 16; m <<= 1) {
#pragma unroll
      for (int r = 0; r < 4; ++r) { s[r] += __shfl_xor(s[r], m); s2[r] += __shfl_xor(s2[r], m); }
    }
    if (qm == 0) {
#pragma unroll
      for (int r = 0; r < 4; ++r) {
        atomicAdd(&stats2[mb + r], s[r]);
        atomicAdd(&stats2[C2 + mb + r], s2[r]);
      }
    }
  }
}

// ---------------- finalize: in-place BN2 + LeakyReLU on out_nf (fp32) ----------------
__global__ __launch_bounds__(256) void finalize_kernel(float* __restrict__ nf,
                                                       const float* __restrict__ aff)
{
  int id4 = blockIdx.x * 256 + threadIdx.x;      // float4-granule index
  int e = id4 * 4;
  int c = (e % (C2 * N0)) / N0;
  float sc = aff[c], sh = aff[C1 + c];
  float4 v = reinterpret_cast<float4*>(nf)[id4];
  v.x = v.x * sc + sh; v.x = (v.x >= 0.f) ? v.x : SLOPE * v.x;
  v.y = v.y * sc + sh; v.y = (v.y >= 0.f) ? v.y : SLOPE * v.y;
  v.z = v.z * sc + sh; v.z = (v.z >= 0.f) ? v.z : SLOPE * v.z;
  v.w = v.w * sc + sh; v.w = (v.w >= 0.f) ? v.w : SLOPE * v.w;
  reinterpret_cast<float4*>(nf)[id4] = v;
}

// ---------------- copy xyz passthrough (fp32) ----------------
__global__ __launch_bounds__(256) void copy_xyz_kernel(const float* __restrict__ xyz,
                                                       float* __restrict__ out)
{
  int id = blockIdx.x * 256 + threadIdx.x;       // float4 granules, 12288 total
  reinterpret_cast<float4*>(out)[id] = reinterpret_cast<const float4*>(xyz)[id];
}

extern "C" void kernel_launch(void* const* d_in, const int* in_sizes, int n_in,
                              void* d_out, int out_size, void* d_ws, size_t ws_size,
                              hipStream_t stream)
{
  const float* xyz       = (const float*)d_in[0];
  const float* skip      = (const float*)d_in[1];
  const float* xyz_prev  = (const float*)d_in[2];
  const float* feat_prev = (const float*)d_in[3];
  const float* W1        = (const float*)d_in[4];
  const float* g1        = (const float*)d_in[5];
  const float* b1        = (const float*)d_in[6];
  const float* W2        = (const float*)d_in[7];
  const float* g2        = (const float*)d_in[8];
  const float* b2        = (const float*)d_in[9];

  float* out    = (float*)d_out;
  float* out_nf = out + (size_t)B * 3 * N0;      // [B][C2][N0] fp32

  char* ws = (char*)d_ws;
  float*          wq    = (float*)(ws + 0);                 //   786432 B
  int*            iq    = (int*)  (ws + 786432);            //   786432 B
  unsigned short* W1b   = (unsigned short*)(ws + 1572864);  //   393216 B
  unsigned short* W2b   = (unsigned short*)(ws + 1966080);  //   131072 B
  float*          stats = (float*)(ws + 2097152);           //     4096 B
  float*          aff   = (float*)(ws + 2101248);           //     4096 B
  unsigned short* Y1t   = (unsigned short*)(ws + 2105344);  // 33554432 B  [COLS][C1]
  unsigned short* Xt    = (unsigned short*)(ws + 35659776); // 100663296 B [COLS][K1]
  // total: 136,323,072 B

  prep_kernel<<<768, 256, 0, stream>>>(W1, W2, W1b, W2b, stats);
  knn_kernel<<<dim3(N0 / 64, B), 256, 0, stream>>>(xyz, xyz_prev, wq, iq);
  interp_kernel<<<512, 256, 0, stream>>>(feat_prev, iq, wq, Xt);
  skipt_kernel<<<4096, 256, 0, stream>>>(skip, Xt);
  gemm1_kernel<<<dim3(512, 2), 256, 0, stream>>>(W1b, Xt, Y1t, stats);
  affine_kernel<<<1, 256, 0, stream>>>(stats, g1, b1, aff);
  gemm2_kernel<<<dim3(512, 2), 256, 0, stream>>>(W2b, Y1t, aff, out_nf, stats + 512);
  affine_kernel<<<1, 256, 0, stream>>>(stats + 512, g2, b2, aff + 512);
  finalize_kernel<<<(C2 * N0 * B) / (4 * 256), 256, 0, stream>>>(out_nf, aff + 512);
  copy_xyz_kernel<<<(B * 3 * N0) / (4 * 256), 256, 0, stream>>>(xyz, out);
}